// Round 3
// baseline (122.702 us; speedup 1.0000x reference)
//
#include <hip/hip_runtime.h>

// Problem constants
#define XDIM  100       // HK*BAG
#define DDIM  512
#define HDIM  512
#define NT    512
// ws layout (bytes)
#define WS_WT2   0          // fp16 Wt2[2][16][512][4][8]   = 1,048,576 B
#define WS_V16   1048576    // fp16 v16[512]                = 1,024 B
#define WS_H16   1049600    // fp16 h16[3200][512]          = 3,276,800 B
#define WS_FP    4326400    // fp32 fp[8][16][100][100]     = 5,120,000 B

typedef _Float16 h16x8 __attribute__((ext_vector_type(8)));
typedef _Float16 h2    __attribute__((ext_vector_type(2)));
typedef float floatx4  __attribute__((ext_vector_type(4)));

union H8U { h16x8 v; h2 p[4]; unsigned u[4]; };

// ---------------------------------------------------------------------------
// prep: Wt2 (mfma-B-fragment-ordered fp16 weights) + v16
__global__ void __launch_bounds__(256) prep_k(const float* __restrict__ W0,
                                              const float* __restrict__ W1,
                                              const float* __restrict__ v,
                                              _Float16* __restrict__ Wt2,
                                              _Float16* __restrict__ v16) {
    int blk = blockIdx.x;
    int t = threadIdx.x;
    if (blk < 2048) {
        // Wt2[w][kb][c][q][8] = W[d=kb*32+q*8+j][c]
        int o  = blk * 256 + t;
        int w  = o >> 18;
        int kb = (o >> 14) & 15;
        int c  = (o >> 5) & 511;
        int qj = o & 31;
        int d  = kb * 32 + qj;
        const float* W = w ? W1 : W0;
        Wt2[o] = (_Float16)W[d * 512 + c];
    } else {
        v16[t * 2]     = (_Float16)v[t * 2];
        v16[t * 2 + 1] = (_Float16)v[t * 2 + 1];
    }
}

// ---------------------------------------------------------------------------
// gemm: h16[hb][m][c] = sum_d fea[hb][m][d] * W{s}[d][c] (+bias if s==1)
// Per wave: 32 rows x 64 cols via 8 accumulators; A converted fp32->fp16
// in-register; B fragments shared across the two m-tiles (halves L2 traffic).
__global__ void __launch_bounds__(256) gemm_k(const float* __restrict__ fea,
                                              const _Float16* __restrict__ Wt2,
                                              const float* __restrict__ bias,
                                              _Float16* __restrict__ h16) {
    int bx   = blockIdx.x;          // 256 = 32 hb * 4 rowtiles(32) * 2 colhalves
    int hb   = bx >> 3;
    int rt   = (bx >> 1) & 3;
    int chal = bx & 1;
    int w    = threadIdx.x >> 6;
    int lane = threadIdx.x & 63;
    int n0   = (chal * 4 + w) * 64;
    int m0   = rt * 32;
    int s    = hb & 1;
    int l15  = lane & 15;
    int q    = lane >> 4;
    int mA   = min(m0 + l15,      XDIM - 1);
    int mB   = min(m0 + 16 + l15, XDIM - 1);

    const float* apA = fea + ((size_t)hb * XDIM + mA) * DDIM + q * 8;
    const float* apB = fea + ((size_t)hb * XDIM + mB) * DDIM + q * 8;
    const _Float16* bp = Wt2 + (size_t)s * 262144 + (size_t)(n0 + l15) * 32 + q * 8;

    floatx4 acc[8] = {};

    for (int kb = 0; kb < 16; ++kb) {
        float4 a0 = *(const float4*)(apA + kb * 32);
        float4 a1 = *(const float4*)(apA + kb * 32 + 4);
        float4 c0 = *(const float4*)(apB + kb * 32);
        float4 c1 = *(const float4*)(apB + kb * 32 + 4);
        h16x8 aA, aB;
        aA[0] = (_Float16)a0.x; aA[1] = (_Float16)a0.y;
        aA[2] = (_Float16)a0.z; aA[3] = (_Float16)a0.w;
        aA[4] = (_Float16)a1.x; aA[5] = (_Float16)a1.y;
        aA[6] = (_Float16)a1.z; aA[7] = (_Float16)a1.w;
        aB[0] = (_Float16)c0.x; aB[1] = (_Float16)c0.y;
        aB[2] = (_Float16)c0.z; aB[3] = (_Float16)c0.w;
        aB[4] = (_Float16)c1.x; aB[5] = (_Float16)c1.y;
        aB[6] = (_Float16)c1.z; aB[7] = (_Float16)c1.w;

        const _Float16* bkb = bp + kb * 16384;
        h16x8 b0 = *(const h16x8*)(bkb);
        h16x8 b1 = *(const h16x8*)(bkb + 512);
        h16x8 b2 = *(const h16x8*)(bkb + 1024);
        h16x8 b3 = *(const h16x8*)(bkb + 1536);
        acc[0] = __builtin_amdgcn_mfma_f32_16x16x32_f16(aA, b0, acc[0], 0, 0, 0);
        acc[4] = __builtin_amdgcn_mfma_f32_16x16x32_f16(aB, b0, acc[4], 0, 0, 0);
        acc[1] = __builtin_amdgcn_mfma_f32_16x16x32_f16(aA, b1, acc[1], 0, 0, 0);
        acc[5] = __builtin_amdgcn_mfma_f32_16x16x32_f16(aB, b1, acc[5], 0, 0, 0);
        acc[2] = __builtin_amdgcn_mfma_f32_16x16x32_f16(aA, b2, acc[2], 0, 0, 0);
        acc[6] = __builtin_amdgcn_mfma_f32_16x16x32_f16(aB, b2, acc[6], 0, 0, 0);
        acc[3] = __builtin_amdgcn_mfma_f32_16x16x32_f16(aA, b3, acc[3], 0, 0, 0);
        acc[7] = __builtin_amdgcn_mfma_f32_16x16x32_f16(aB, b3, acc[7], 0, 0, 0);
    }

    _Float16* hob = h16 + (size_t)hb * (XDIM * HDIM);
    #pragma unroll
    for (int mt = 0; mt < 2; ++mt) {
        #pragma unroll
        for (int j = 0; j < 4; ++j) {
            floatx4 a = acc[mt * 4 + j];
            int col = n0 + 16 * j + l15;
            float bi = s ? bias[col] : 0.f;
            #pragma unroll
            for (int r = 0; r < 4; ++r) {
                int mr = m0 + mt * 16 + q * 4 + r;
                if (mr < XDIM) hob[(size_t)mr * HDIM + col] = (_Float16)(a[r] + bi);
            }
        }
    }
}

// ---------------------------------------------------------------------------
// full: fp[ks][b][x][y] = sum_{h in chunk ks} relu(h0[x,h]+h1[y,h])*v[h]
// 64x64 tile / block, 4x4 per thread, packed fp16 + v_dot2. Also writes pairs.
__global__ void __launch_bounds__(256) full_k(const _Float16* __restrict__ h16,
                                              const _Float16* __restrict__ v16,
                                              float* __restrict__ fp,
                                              float2* __restrict__ pout) {
    int bx  = blockIdx.x;           // 512 = 8 ks * 16 b * 2 xt * 2 yt
    int ks  = bx >> 6;
    int rem = bx & 63;
    int b   = rem >> 2;
    int xt  = (rem >> 1) & 1;
    int yt  = rem & 1;
    int x0  = xt * 36;              // tiles [0,64) and [36,100): overlap writes same values
    int y0  = yt * 36;
    int kc  = ks * 64;

    __shared__ _Float16 sh0[64][72];      // [x][k], stride 72 fp16 (bank-safe)
    __shared__ unsigned sh1p[32][64];     // [kpair][y] packed h2
    __shared__ unsigned sv[32];           // v pairs

    int t = threadIdx.x;
    int r = t & 63, kseg = t >> 6;

    const _Float16* g0 = h16 + ((size_t)(b * 2) * XDIM + x0 + r) * HDIM + kc + kseg * 16;
    *(h16x8*)&sh0[r][kseg * 16]     = *(const h16x8*)g0;
    *(h16x8*)&sh0[r][kseg * 16 + 8] = *(const h16x8*)(g0 + 8);

    const _Float16* g1 = h16 + ((size_t)(b * 2 + 1) * XDIM + y0 + r) * HDIM + kc + kseg * 16;
    H8U u0, u1;
    u0.v = *(const h16x8*)g1;
    u1.v = *(const h16x8*)(g1 + 8);
    #pragma unroll
    for (int pp = 0; pp < 4; ++pp) {
        sh1p[kseg * 8 + pp][r]     = u0.u[pp];
        sh1p[kseg * 8 + 4 + pp][r] = u1.u[pp];
    }
    if (t < 32) sv[t] = *(const unsigned*)(v16 + kc + t * 2);
    __syncthreads();

    // pairs meshgrid: pure stores, drain under the compute below
    {
        size_t pbase = (size_t)bx * 8192;
        #pragma unroll 4
        for (int i = 0; i < 32; ++i) {
            unsigned idx = (unsigned)(pbase + i * 256 + t);
            float2 pr;
            pr.x = (float)((idx >> 9) & 511);
            pr.y = (float)(idx & 511);
            pout[idx] = pr;
        }
    }

    int ty = t >> 4, tx = t & 15;
    float acc[4][4] = {};
    h2 hz; hz[0] = (_Float16)0; hz[1] = (_Float16)0;

    for (int kk = 0; kk < 8; ++kk) {
        H8U a[4];
        #pragma unroll
        for (int i = 0; i < 4; ++i)
            a[i].v = *(const h16x8*)&sh0[ty * 4 + i][kk * 8];
        uint4 bq[4];
        #pragma unroll
        for (int p = 0; p < 4; ++p)
            bq[p] = *(const uint4*)&sh1p[kk * 4 + p][tx * 4];
        uint4 vq = *(const uint4*)&sv[kk * 4];
        const unsigned* vqa = (const unsigned*)&vq;

        #pragma unroll
        for (int p = 0; p < 4; ++p) {
            h2 vp = __builtin_bit_cast(h2, vqa[p]);
            const unsigned* bqa = (const unsigned*)&bq[p];
            #pragma unroll
            for (int i = 0; i < 4; ++i) {
                h2 av = a[i].p[p];
                #pragma unroll
                for (int j = 0; j < 4; ++j) {
                    h2 s = av + __builtin_bit_cast(h2, bqa[j]);
                    s = __builtin_elementwise_max(s, hz);
#if __has_builtin(__builtin_amdgcn_fdot2)
                    acc[i][j] = __builtin_amdgcn_fdot2(s, vp, acc[i][j], false);
#else
                    acc[i][j] += (float)s[0] * (float)vp[0] + (float)s[1] * (float)vp[1];
#endif
                }
            }
        }
    }

    float* fpb = fp + (size_t)(ks * 16 + b) * (XDIM * XDIM);
    #pragma unroll
    for (int i = 0; i < 4; ++i) {
        float4 o;
        o.x = acc[i][0]; o.y = acc[i][1]; o.z = acc[i][2]; o.w = acc[i][3];
        *(float4*)&fpb[(size_t)(x0 + ty * 4 + i) * XDIM + y0 + tx * 4] = o;
    }
}

// ---------------------------------------------------------------------------
// score: pooled[b][i][j] = sum_ks sum_{rows a0,a1} sum_{cols c0,c1} fp[...]
__global__ void __launch_bounds__(256) score_k(const float* __restrict__ fp,
                                               const int* __restrict__ ind0,
                                               const int* __restrict__ ind1,
                                               float* __restrict__ out) {
    int bx  = blockIdx.x;           // 512 = 16 b * 16 itiles * 2 jhalves
    int b   = bx >> 5;
    int rem = bx & 31;
    int it  = rem >> 1;
    int jh  = rem & 1;
    int i0  = it * 32;

    __shared__ float rowsum[32][100];
    __shared__ int a0s[32], a1s[32];
    __shared__ int c0s[256], c1s[256];

    int t = threadIdx.x;
    if (t < 32) {
        int2 ii = *(const int2*)(ind0 + ((size_t)b * NT + i0 + t) * 2);
        a0s[t] = ii.x;
        a1s[t] = ii.y + 50;
    }
    {
        int2 jj = *(const int2*)(ind1 + ((size_t)b * NT + jh * 256 + t) * 2);
        c0s[t] = jj.x;
        c1s[t] = jj.y + 50;
    }
    __syncthreads();

    const float* fb = fp + (size_t)b * (XDIM * XDIM);
    for (int idx = t; idx < 1024; idx += 256) {
        int il = idx >> 5, yq = idx & 31;
        if (yq < 25) {
            float4 s = {0.f, 0.f, 0.f, 0.f};
            int a0 = a0s[il] * XDIM + yq * 4;
            int a1 = a1s[il] * XDIM + yq * 4;
            #pragma unroll
            for (int ksb = 0; ksb < 8; ++ksb) {
                const float* pl = fb + (size_t)ksb * (16 * XDIM * XDIM);
                float4 u = *(const float4*)(pl + a0);
                float4 w = *(const float4*)(pl + a1);
                s.x += u.x + w.x; s.y += u.y + w.y;
                s.z += u.z + w.z; s.w += u.w + w.w;
            }
            *(float4*)&rowsum[il][yq * 4] = s;
        }
    }
    __syncthreads();

    float* sout = out + (size_t)b * (NT * NT) + (size_t)i0 * NT + jh * 256;
    for (int o = t; o < 8192; o += 256) {
        int il = o >> 8, jl = o & 255;
        sout[(size_t)il * NT + jl] = rowsum[il][c0s[jl]] + rowsum[il][c1s[jl]];
    }
}

// ---------------------------------------------------------------------------
extern "C" void kernel_launch(void* const* d_in, const int* in_sizes, int n_in,
                              void* d_out, int out_size, void* d_ws, size_t ws_size,
                              hipStream_t stream) {
    const float* fea  = (const float*)d_in[0];
    const int*   ind0 = (const int*)d_in[1];
    const int*   ind1 = (const int*)d_in[2];
    const float* W0   = (const float*)d_in[3];
    const float* W1   = (const float*)d_in[4];
    const float* bias = (const float*)d_in[5];
    const float* v    = (const float*)d_in[6];
    float* out = (float*)d_out;
    char*  ws  = (char*)d_ws;

    _Float16* Wt2 = (_Float16*)(ws + WS_WT2);
    _Float16* v16 = (_Float16*)(ws + WS_V16);
    _Float16* h16 = (_Float16*)(ws + WS_H16);
    float*    fp  = (float*)(ws + WS_FP);
    float2*   pout = (float2*)(out + (size_t)16 * NT * NT);

    hipLaunchKernelGGL(prep_k,  dim3(2049), dim3(256), 0, stream, W0, W1, v, Wt2, v16);
    hipLaunchKernelGGL(gemm_k,  dim3(256),  dim3(256), 0, stream, fea, Wt2, bias, h16);
    hipLaunchKernelGGL(full_k,  dim3(512),  dim3(256), 0, stream, h16, v16, fp, pout);
    hipLaunchKernelGGL(score_k, dim3(512),  dim3(256), 0, stream, fp, ind0, ind1, out);
}